// Round 14
// baseline (118.818 us; speedup 1.0000x reference)
//
#include <hip/hip_runtime.h>

typedef unsigned short u16;
typedef __attribute__((ext_vector_type(8))) __bf16 bf16x8;
typedef __attribute__((ext_vector_type(8))) u16 u16x8;
typedef __attribute__((ext_vector_type(4))) u16 u16x4;
typedef __attribute__((ext_vector_type(4))) float f32x4;

#define DEV __device__ __forceinline__

// ---------- helpers ----------
DEV u16 f2bf(float f) {  // RTNE fp32 -> bf16
  union { float f; unsigned u; } x; x.f = f;
  unsigned u = x.u;
  u += 0x7fffu + ((u >> 16) & 1u);
  return (u16)(u >> 16);
}

DEV void gload16(const void* g, void* l) {  // async global->LDS, 16B/lane
  __builtin_amdgcn_global_load_lds(
      (const __attribute__((address_space(1))) void*)g,
      (__attribute__((address_space(3))) void*)l, 16, 0, 0);
}

DEV f32x4 mfma16(bf16x8 a, bf16x8 b, f32x4 c) {
  return __builtin_amdgcn_mfma_f32_16x16x32_bf16(a, b, c, 0, 0, 0);
}

DEV void bar() {
  asm volatile("" ::: "memory");
  __builtin_amdgcn_s_barrier();
  asm volatile("" ::: "memory");
}

// truncating f32->bf16 store to LDS: writes high 16 bits, zero VALU convert
DEV void st_p_hi(void* lptr, float v) {
  unsigned a3 = (unsigned)(size_t)(__attribute__((address_space(3))) void*)lptr;
  asm volatile("ds_write_b16_d16_hi %0, %1" :: "v"(a3), "v"(v));
}

// ---------- sizes ----------
#define SEQ   2048
#define EMB   1024
#define MROWS 4096            // B*S
#define NQKV  3072
#define HID   64              // head dim
#define PRESENT_HALF 4194304  // B*H*S*Dh elements
// fold 1/sqrt(64) * log2(e) into Q so softmax uses exp2 directly
#define QSCALE 0.1803368801f

// ---------- fp32 -> bf16 convert (8 elems/thread) ----------
__global__ void k_convert(const float* __restrict__ src, u16* __restrict__ dst, int n8) {
  int i = blockIdx.x * blockDim.x + threadIdx.x;
  if (i >= n8) return;
  const float4* s = (const float4*)src + (size_t)i * 2;
  float4 a = s[0], b = s[1];
  u16x8 r;
  r[0] = f2bf(a.x); r[1] = f2bf(a.y); r[2] = f2bf(a.z); r[3] = f2bf(a.w);
  r[4] = f2bf(b.x); r[5] = f2bf(b.y); r[6] = f2bf(b.z); r[7] = f2bf(b.w);
  *((u16x8*)dst + i) = r;
}

// ---------- transpose+convert: src f32 [K][N] -> dst bf16 [N][K] ----------
__global__ void k_transpose(const float* __restrict__ src, u16* __restrict__ dst,
                            int K, int N) {
  __shared__ __attribute__((aligned(16))) u16 t[32][33];
  int n0 = blockIdx.x * 32, k0 = blockIdx.y * 32;
  for (int i = threadIdx.x; i < 1024; i += 256) {
    int r = i >> 5, c = i & 31;
    t[r][c] = f2bf(src[(size_t)(k0 + r) * N + (n0 + c)]);
  }
  __syncthreads();
  for (int i = threadIdx.x; i < 1024; i += 256) {
    int r = i >> 5, c = i & 31;
    dst[(size_t)(n0 + r) * K + (k0 + c)] = t[c][r];
  }
}

// ---------- shared GEMM core: C[128,128] tile, 3-buffer 1-ahead pipeline,
// SINGLE barrier per K-step (verified round 13). ----------
DEV void gemm_core(const u16* __restrict__ A, const u16* __restrict__ Bt, int K,
                   int brow, int bcol, u16* As, u16* Bs, f32x4 acc[4][4]) {
  int tid = threadIdx.x, lane = tid & 63, wid = tid >> 6;
  int wr = (wid >> 1) * 64, wc = (wid & 1) * 64;
  int r = lane & 15, kkb = (lane >> 4) * 16;
  const char* Ab = (const char*)(A + (size_t)(brow + (tid >> 2)) * K) + (tid & 3) * 16;
  const char* Bb = (const char*)(Bt + (size_t)(bcol + (tid >> 2)) * K) + (tid & 3) * 16;
  char* Ad = (char*)As + tid * 16;
  char* Bd = (char*)Bs + tid * 16;
  const size_t rowskip = (size_t)64 * K * 2;
#define GSTAGE(k0v, b) do { size_t kb2 = (size_t)(k0v) * 2;            \
    gload16(Ab + kb2, Ad + (b) * 8192);                                \
    gload16(Ab + kb2 + rowskip, Ad + (b) * 8192 + 4096);               \
    gload16(Bb + kb2, Bd + (b) * 8192);                                \
    gload16(Bb + kb2 + rowskip, Bd + (b) * 8192 + 4096); } while (0)
  GSTAGE(0, 0);
  int nk = K >> 5;  // >= 3
  for (int i = 0; i < nk; ++i) {
    int cur = i % 3;
    if (i < nk - 1) {
      GSTAGE((i + 1) << 5, (i + 1) % 3);
      asm volatile("s_waitcnt vmcnt(4)" ::: "memory");  // tile i landed
    } else {
      asm volatile("s_waitcnt vmcnt(0)" ::: "memory");
    }
    bar();
    const char* Ac = (const char*)As + cur * 8192;
    const char* Bc = (const char*)Bs + cur * 8192;
    bf16x8 af[4], bfr[4];
#pragma unroll
    for (int m = 0; m < 4; ++m)
      af[m] = *(const bf16x8*)(Ac + (wr + m * 16 + r) * 64 + kkb);
#pragma unroll
    for (int n = 0; n < 4; ++n)
      bfr[n] = *(const bf16x8*)(Bc + (wc + n * 16 + r) * 64 + kkb);
#pragma unroll
    for (int m = 0; m < 4; ++m)
#pragma unroll
      for (int n = 0; n < 4; ++n)
        acc[m][n] = mfma16(af[m], bfr[n], acc[m][n]);
    // no tail barrier: NB=3 with 1-ahead prefetch makes the WAR window empty
  }
#undef GSTAGE
}

// XCD-aware bijective block swizzle (grid size divisible by 8)
DEV void xcd_swz(int nbx, int nby, int& bx, int& by) {
  int nwg = nbx * nby;
  int bid = by * nbx + bx;
  int cpx = nwg >> 3;
  int s = (bid & 7) * cpx + (bid >> 3);
  bx = s % nbx;
  by = s / nbx;
}

// ---------- QKV GEMM + scatter epilogue (V written pre-transposed) ----------
__global__ void k_gemm_qkv(const u16* __restrict__ A, const u16* __restrict__ Bt,
                           const float* __restrict__ bias, u16* __restrict__ qb,
                           u16* __restrict__ kb, u16* __restrict__ vt,
                           float* __restrict__ present) {
  __shared__ __attribute__((aligned(16))) u16 As[3 * 4096];
  __shared__ __attribute__((aligned(16))) u16 Bs[3 * 4096];
  f32x4 acc[4][4];
#pragma unroll
  for (int m = 0; m < 4; ++m)
#pragma unroll
    for (int n = 0; n < 4; ++n) acc[m][n] = {0.f, 0.f, 0.f, 0.f};
  int bx = blockIdx.x, by = blockIdx.y;
  xcd_swz(24, 32, bx, by);
  int brow = by * 128, bcol = bx * 128;
  gemm_core(A, Bt, EMB, brow, bcol, As, Bs, acc);
  int tid = threadIdx.x, lane = tid & 63, wid = tid >> 6;
  int wr = (wid >> 1) * 64, wc = (wid & 1) * 64;
  int r = lane & 15, rj = (lane >> 4) * 4;
#pragma unroll
  for (int m = 0; m < 4; ++m)
#pragma unroll
    for (int n = 0; n < 4; ++n) {
      int gc = bcol + wc + n * 16 + r;
      int t = gc >> 10, e = gc & 1023, h = e >> 6, dh = e & 63;
      float bv = bias[gc];
      float v4[4];
#pragma unroll
      for (int j = 0; j < 4; ++j) v4[j] = acc[m][n][j] + bv;
      int gr0 = brow + wr + m * 16 + rj;          // j adds 0..3 (same 2048-page)
      size_t bh16 = (size_t)((gr0 >> 11) * 16 + h);
      int s0 = gr0 & 2047;
      if (t == 0) {
#pragma unroll
        for (int j = 0; j < 4; ++j)
          qb[(bh16 * SEQ + s0 + j) * HID + dh] = f2bf(v4[j] * QSCALE);
      } else if (t == 1) {
#pragma unroll
        for (int j = 0; j < 4; ++j) {
          size_t hidx = (bh16 * SEQ + s0 + j) * HID + dh;
          kb[hidx] = f2bf(v4[j]);
          present[hidx] = v4[j];
        }
      } else {
        u16x4 pk;
#pragma unroll
        for (int j = 0; j < 4; ++j) pk[j] = f2bf(v4[j]);
        *(u16x4*)&vt[(bh16 * HID + dh) * SEQ + s0] = pk;  // 4 consecutive s, 8B
#pragma unroll
        for (int j = 0; j < 4; ++j)
          present[(size_t)PRESENT_HALF + (bh16 * SEQ + s0 + j) * HID + dh] = v4[j];
      }
    }
}

// ---------- proj GEMM ----------
__global__ void k_gemm_proj(const u16* __restrict__ A, const u16* __restrict__ Bt,
                            const float* __restrict__ bias, float* __restrict__ out) {
  __shared__ __attribute__((aligned(16))) u16 As[3 * 4096];
  __shared__ __attribute__((aligned(16))) u16 Bs[3 * 4096];
  f32x4 acc[4][4];
#pragma unroll
  for (int m = 0; m < 4; ++m)
#pragma unroll
    for (int n = 0; n < 4; ++n) acc[m][n] = {0.f, 0.f, 0.f, 0.f};
  int bx = blockIdx.x, by = blockIdx.y;
  xcd_swz(8, 32, bx, by);
  int brow = by * 128, bcol = bx * 128;
  gemm_core(A, Bt, EMB, brow, bcol, As, Bs, acc);
  int tid = threadIdx.x, lane = tid & 63, wid = tid >> 6;
  int wr = (wid >> 1) * 64, wc = (wid & 1) * 64;
  int r = lane & 15, rj = (lane >> 4) * 4;
#pragma unroll
  for (int m = 0; m < 4; ++m)
#pragma unroll
    for (int n = 0; n < 4; ++n) {
      int gc = bcol + wc + n * 16 + r;
      float bv = bias[gc];
#pragma unroll
      for (int j = 0; j < 4; ++j) {
        int gr = brow + wr + m * 16 + rj + j;
        out[(size_t)gr * EMB + gc] = acc[m][n][j] + bv;
      }
    }
}

// ---------- causal flash attention: one 128-row q-tile per block, 8 waves.
// Per-wave datapath identical to the verified 4-wave version (each wave owns
// 16 q-rows); K/V staged ONCE per 128 q-rows (staging, barriers, vmcnt per
// q-row all halve).  Grid 512 blocks = 2/CU (LDS 48KB); co-resident blocks
// {c, c+256} get t = {15-s, s} (per-CU iteration sum = 36 const), same bh.
__global__ __launch_bounds__(512, 4) void k_attn(
    const u16* __restrict__ qb, const u16* __restrict__ kb,
    const u16* __restrict__ vt, u16* __restrict__ ao) {
  __shared__ __attribute__((aligned(16))) u16 Ks[2][4096];
  __shared__ __attribute__((aligned(16))) u16 Vs[2][4096];  // V^T tiles [dh][k]
  __shared__ __attribute__((aligned(16))) u16 Ps[8192];     // 8 waves x 2KB
  int tid = threadIdx.x, lane = tid & 63, w = tid >> 6;      // w in 0..7
  int r = lane & 15, g = lane >> 4, kkb = g * 16;
  int bid = blockIdx.x;
  int p = bid >> 5, bh = bid & 31;
  int t = (p < 8) ? (15 - p) : (p - 8);
  int q0 = t * 128;
  int ktmax = 2 * t + 1;
  const char* Kbh = (const char*)kb + (size_t)bh * SEQ * 128;      // tile kt at +kt*8192
  const char* Vbh = (const char*)vt + (size_t)bh * HID * SEQ * 2;  // row stride 4096B

  // Q fragments (Q pre-scaled by 1/8*log2e)
  size_t qr = (size_t)bh * SEQ + q0 + w * 16 + r;
  bf16x8 aq0 = *(const bf16x8*)((const char*)qb + qr * 128 + kkb);
  bf16x8 aq1 = *(const bf16x8*)((const char*)qb + qr * 128 + 64 + kkb);

  f32x4 o[4];
  float l[4];
#pragma unroll
  for (int d = 0; d < 4; ++d) o[d] = {0.f, 0.f, 0.f, 0.f};
#pragma unroll
  for (int j = 0; j < 4; ++j) l[j] = 0.f;

  // staging: 512 threads x 16B = one full 8KB tile per gload.
  // linear LDS dest, inverse-swizzled global source (rule #21)
  int lin = tid * 16;                        // 0..8176
  int lrow = lin >> 7;
  int ksrc = lin ^ ((lrow & 7) << 4);
  int vcol = (lin & 127) ^ ((lrow & 7) << 4);

#define STAGE(kt, b) do {                                                 \
    gload16(Kbh + (size_t)(kt) * 8192 + ksrc, (char*)Ks[b] + lin);        \
    gload16(Vbh + (size_t)(kt) * 128 + (size_t)lrow * 4096 + vcol,        \
            (char*)Vs[b] + lin);                                          \
  } while (0)

  char* Pw = (char*)Ps + w * 2048;
  int swz = (r & 7) << 4;

  STAGE(0, 0);
  for (int kt = 0; kt <= ktmax; ++kt) {
    int cur = kt & 1;
    if (kt < ktmax) {
      STAGE(kt + 1, cur ^ 1);
      asm volatile("s_waitcnt vmcnt(2)" ::: "memory");
    } else {
      asm volatile("s_waitcnt vmcnt(0)" ::: "memory");
    }
    bar();
    const char* Kc = (const char*)Ks[cur];
    const char* Vc = (const char*)Vs[cur];

    // QK^T
    f32x4 s[4];
    __builtin_amdgcn_s_setprio(1);
#pragma unroll
    for (int kc = 0; kc < 4; ++kc) {
      int rowb = (kc * 16 + r) * 128;
      bf16x8 bk0 = *(const bf16x8*)(Kc + ((rowb + kkb) ^ swz));
      bf16x8 bk1 = *(const bf16x8*)(Kc + ((rowb + 64 + kkb) ^ swz));
      f32x4 sv = {0.f, 0.f, 0.f, 0.f};
      sv = mfma16(aq0, bk0, sv);
      sv = mfma16(aq1, bk1, sv);
      s[kc] = sv;
    }
    __builtin_amdgcn_s_setprio(0);
    // causal mask (diagonal region only)
    if (kt * 64 + 63 > q0 + w * 16) {
      int qg = q0 + w * 16 + g * 4;
#pragma unroll
      for (int kc = 0; kc < 4; ++kc) {
        int kg = kt * 64 + kc * 16 + r;
#pragma unroll
        for (int j = 0; j < 4; ++j)
          if (kg > qg + j) s[kc][j] = -1e30f;
      }
    }
    // fixed-max softmax: P = exp2(s); per-lane partial row sums, no shuffles.
    // P store = truncating ds_write_b16_d16_hi (zero-VALU bf16 convert).
#pragma unroll
    for (int kc = 0; kc < 4; ++kc)
#pragma unroll
      for (int j = 0; j < 4; ++j) {
        int row = g * 4 + j;
        int byt = (row * 128 + kc * 32 + r * 2) ^ ((row & 7) << 4);
        float pv = __builtin_amdgcn_exp2f(s[kc][j]);
        l[j] += pv;
        st_p_hi(Pw + byt, pv);
      }
    asm volatile("" ::: "memory");  // fence: PV reads must not hoist above P stores
    // PV with shared V fragments
    __builtin_amdgcn_s_setprio(1);
#pragma unroll
    for (int kk2 = 0; kk2 < 2; ++kk2) {
      int pbyt = (r * 128 + kk2 * 64 + kkb) ^ swz;
      bf16x8 ap = *(const bf16x8*)(Pw + pbyt);
#pragma unroll
      for (int d = 0; d < 4; ++d) {
        int vrow = (d * 16 + r) * 128;
        bf16x8 bv = *(const bf16x8*)(Vc + ((vrow + kk2 * 64 + kkb) ^ swz));
        o[d] = mfma16(ap, bv, o[d]);
      }
    }
    __builtin_amdgcn_s_setprio(0);
    // drain DS returns (incl. untracked asm writes) before next DMA overwrite
    asm volatile("s_waitcnt lgkmcnt(0)" ::: "memory");
    bar();
  }
#undef STAGE

  int b = bh >> 4, h = bh & 15;
#pragma unroll
  for (int j = 0; j < 4; ++j) {
    float sr = l[j];
    sr += __shfl_xor(sr, 1);
    sr += __shfl_xor(sr, 2);
    sr += __shfl_xor(sr, 4);
    sr += __shfl_xor(sr, 8);
    float inv = 1.f / sr;
    size_t row = (size_t)b * SEQ + q0 + w * 16 + g * 4 + j;
#pragma unroll
    for (int d = 0; d < 4; ++d)
      ao[row * EMB + h * 64 + d * 16 + r] = f2bf(o[d][j] * inv);
  }
}

// ---------- launch ----------
extern "C" void kernel_launch(void* const* d_in, const int* in_sizes, int n_in,
                              void* d_out, int out_size, void* d_ws, size_t ws_size,
                              hipStream_t stream) {
  const float* x = (const float*)d_in[0];
  const float* W_attn = (const float*)d_in[1];
  const float* b_attn = (const float*)d_in[2];
  const float* W_proj = (const float*)d_in[3];
  const float* b_proj = (const float*)d_in[4];
  float* out = (float*)d_out;
  char* ws = (char*)d_ws;
  u16* xb  = (u16*)(ws + 0);          //  8 MB  x bf16 [4096][1024]
  u16* wat = (u16*)(ws + 8388608);    //  6 MB  W_attn^T bf16 [3072][1024]
  u16* wpt = (u16*)(ws + 14680064);   //  2 MB  W_proj^T bf16 [1024][1024]
  u16* qb  = (u16*)(ws + 16777216);   //  8 MB  q bf16 [B,H,S,64] (pre-scaled)
  u16* kb  = (u16*)(ws + 25165824);   //  8 MB  k bf16 [B,H,S,64]
  u16* vtb = (u16*)(ws + 33554432);   //  8 MB  v^T bf16 [B,H,64,S]
  u16* ao  = (u16*)(ws + 41943040);   //  8 MB  attn out bf16 [4096][1024]
  float* present = out + PRESENT_HALF;

  k_convert<<<dim3(2048), 256, 0, stream>>>(x, xb, 524288);
  k_transpose<<<dim3(96, 32), 256, 0, stream>>>(W_attn, wat, EMB, NQKV);
  k_transpose<<<dim3(32, 32), 256, 0, stream>>>(W_proj, wpt, EMB, EMB);
  k_gemm_qkv<<<dim3(24, 32), 256, 0, stream>>>(xb, wat, b_attn, qb, kb, vtb, present);
  k_attn<<<dim3(512), 512, 0, stream>>>(qb, kb, vtb, ao);
  k_gemm_proj<<<dim3(8, 32), 256, 0, stream>>>(ao, wpt, b_proj, out);
}

// Round 15
// 109.320 us; speedup vs baseline: 1.0869x; 1.0869x over previous
//
#include <hip/hip_runtime.h>

typedef unsigned short u16;
typedef __attribute__((ext_vector_type(8))) __bf16 bf16x8;
typedef __attribute__((ext_vector_type(8))) u16 u16x8;
typedef __attribute__((ext_vector_type(4))) u16 u16x4;
typedef __attribute__((ext_vector_type(4))) float f32x4;

#define DEV __device__ __forceinline__

// ---------- helpers ----------
DEV u16 f2bf(float f) {  // RTNE fp32 -> bf16
  union { float f; unsigned u; } x; x.f = f;
  unsigned u = x.u;
  u += 0x7fffu + ((u >> 16) & 1u);
  return (u16)(u >> 16);
}

DEV void gload16(const void* g, void* l) {  // async global->LDS, 16B/lane
  __builtin_amdgcn_global_load_lds(
      (const __attribute__((address_space(1))) void*)g,
      (__attribute__((address_space(3))) void*)l, 16, 0, 0);
}

DEV f32x4 mfma16(bf16x8 a, bf16x8 b, f32x4 c) {
  return __builtin_amdgcn_mfma_f32_16x16x32_bf16(a, b, c, 0, 0, 0);
}

DEV void bar() {
  asm volatile("" ::: "memory");
  __builtin_amdgcn_s_barrier();
  asm volatile("" ::: "memory");
}

// truncating f32->bf16 store to LDS: writes high 16 bits, zero VALU convert
DEV void st_p_hi(void* lptr, float v) {
  unsigned a3 = (unsigned)(size_t)(__attribute__((address_space(3))) void*)lptr;
  asm volatile("ds_write_b16_d16_hi %0, %1" :: "v"(a3), "v"(v));
}

// ---------- sizes ----------
#define SEQ   2048
#define EMB   1024
#define MROWS 4096            // B*S
#define NQKV  3072
#define HID   64              // head dim
#define PRESENT_HALF 4194304  // B*H*S*Dh elements
// fold 1/sqrt(64) * log2(e) into Q so softmax uses exp2 directly
#define QSCALE 0.1803368801f

// ---------- merged prep: x convert + both weight transposes, one launch ----
// blocks [0,2048): convert x (8 elems/thread)
// blocks [2048,5120): transpose W_attn f32[1024][3072] -> bf16 [3072][1024]
// blocks [5120,6144): transpose W_proj f32[1024][1024] -> bf16 [1024][1024]
DEV void transpose_tile(const float* __restrict__ src, u16* __restrict__ dst,
                        int K, int N, int bx, int by, u16 (*t)[33]) {
  int n0 = bx * 32, k0 = by * 32;
  for (int i = threadIdx.x; i < 1024; i += 256) {
    int r = i >> 5, c = i & 31;
    t[r][c] = f2bf(src[(size_t)(k0 + r) * N + (n0 + c)]);
  }
  __syncthreads();
  for (int i = threadIdx.x; i < 1024; i += 256) {
    int r = i >> 5, c = i & 31;
    dst[(size_t)(n0 + r) * K + (k0 + c)] = t[c][r];
  }
}

__global__ void k_prep(const float* __restrict__ x, u16* __restrict__ xb,
                       const float* __restrict__ W_attn, u16* __restrict__ wat,
                       const float* __restrict__ W_proj, u16* __restrict__ wpt) {
  __shared__ __attribute__((aligned(16))) u16 t[32][33];
  int bid = blockIdx.x;
  if (bid < 2048) {
    int i = bid * 256 + threadIdx.x;  // < 524288
    const float4* s = (const float4*)x + (size_t)i * 2;
    float4 a = s[0], b = s[1];
    u16x8 r;
    r[0] = f2bf(a.x); r[1] = f2bf(a.y); r[2] = f2bf(a.z); r[3] = f2bf(a.w);
    r[4] = f2bf(b.x); r[5] = f2bf(b.y); r[6] = f2bf(b.z); r[7] = f2bf(b.w);
    *((u16x8*)xb + i) = r;
  } else if (bid < 5120) {
    int b = bid - 2048;  // 96 x 32 tiles
    transpose_tile(W_attn, wat, EMB, NQKV, b % 96, b / 96, t);
  } else {
    int b = bid - 5120;  // 32 x 32 tiles
    transpose_tile(W_proj, wpt, EMB, EMB, b % 32, b / 32, t);
  }
}

// ---------- shared GEMM core: C[128,128] tile, 3-buffer 1-ahead pipeline,
// SINGLE barrier per K-step (verified round 13). ----------
DEV void gemm_core(const u16* __restrict__ A, const u16* __restrict__ Bt, int K,
                   int brow, int bcol, u16* As, u16* Bs, f32x4 acc[4][4]) {
  int tid = threadIdx.x, lane = tid & 63, wid = tid >> 6;
  int wr = (wid >> 1) * 64, wc = (wid & 1) * 64;
  int r = lane & 15, kkb = (lane >> 4) * 16;
  const char* Ab = (const char*)(A + (size_t)(brow + (tid >> 2)) * K) + (tid & 3) * 16;
  const char* Bb = (const char*)(Bt + (size_t)(bcol + (tid >> 2)) * K) + (tid & 3) * 16;
  char* Ad = (char*)As + tid * 16;
  char* Bd = (char*)Bs + tid * 16;
  const size_t rowskip = (size_t)64 * K * 2;
#define GSTAGE(k0v, b) do { size_t kb2 = (size_t)(k0v) * 2;            \
    gload16(Ab + kb2, Ad + (b) * 8192);                                \
    gload16(Ab + kb2 + rowskip, Ad + (b) * 8192 + 4096);               \
    gload16(Bb + kb2, Bd + (b) * 8192);                                \
    gload16(Bb + kb2 + rowskip, Bd + (b) * 8192 + 4096); } while (0)
  GSTAGE(0, 0);
  int nk = K >> 5;  // >= 3
  for (int i = 0; i < nk; ++i) {
    int cur = i % 3;
    if (i < nk - 1) {
      GSTAGE((i + 1) << 5, (i + 1) % 3);
      asm volatile("s_waitcnt vmcnt(4)" ::: "memory");  // tile i landed
    } else {
      asm volatile("s_waitcnt vmcnt(0)" ::: "memory");
    }
    bar();
    const char* Ac = (const char*)As + cur * 8192;
    const char* Bc = (const char*)Bs + cur * 8192;
    bf16x8 af[4], bfr[4];
#pragma unroll
    for (int m = 0; m < 4; ++m)
      af[m] = *(const bf16x8*)(Ac + (wr + m * 16 + r) * 64 + kkb);
#pragma unroll
    for (int n = 0; n < 4; ++n)
      bfr[n] = *(const bf16x8*)(Bc + (wc + n * 16 + r) * 64 + kkb);
#pragma unroll
    for (int m = 0; m < 4; ++m)
#pragma unroll
      for (int n = 0; n < 4; ++n)
        acc[m][n] = mfma16(af[m], bfr[n], acc[m][n]);
    // no tail barrier: NB=3 with 1-ahead prefetch makes the WAR window empty
  }
#undef GSTAGE
}

// XCD-aware bijective block swizzle (grid size divisible by 8)
DEV void xcd_swz(int nbx, int nby, int& bx, int& by) {
  int nwg = nbx * nby;
  int bid = by * nbx + bx;
  int cpx = nwg >> 3;
  int s = (bid & 7) * cpx + (bid >> 3);
  bx = s % nbx;
  by = s / nbx;
}

// ---------- QKV GEMM + scatter epilogue (V written pre-transposed) ----------
__global__ void k_gemm_qkv(const u16* __restrict__ A, const u16* __restrict__ Bt,
                           const float* __restrict__ bias, u16* __restrict__ qb,
                           u16* __restrict__ kb, u16* __restrict__ vt,
                           float* __restrict__ present) {
  __shared__ __attribute__((aligned(16))) u16 As[3 * 4096];
  __shared__ __attribute__((aligned(16))) u16 Bs[3 * 4096];
  f32x4 acc[4][4];
#pragma unroll
  for (int m = 0; m < 4; ++m)
#pragma unroll
    for (int n = 0; n < 4; ++n) acc[m][n] = {0.f, 0.f, 0.f, 0.f};
  int bx = blockIdx.x, by = blockIdx.y;
  xcd_swz(24, 32, bx, by);
  int brow = by * 128, bcol = bx * 128;
  gemm_core(A, Bt, EMB, brow, bcol, As, Bs, acc);
  int tid = threadIdx.x, lane = tid & 63, wid = tid >> 6;
  int wr = (wid >> 1) * 64, wc = (wid & 1) * 64;
  int r = lane & 15, rj = (lane >> 4) * 4;
#pragma unroll
  for (int m = 0; m < 4; ++m)
#pragma unroll
    for (int n = 0; n < 4; ++n) {
      int gc = bcol + wc + n * 16 + r;
      int t = gc >> 10, e = gc & 1023, h = e >> 6, dh = e & 63;
      float bv = bias[gc];
      float v4[4];
#pragma unroll
      for (int j = 0; j < 4; ++j) v4[j] = acc[m][n][j] + bv;
      int gr0 = brow + wr + m * 16 + rj;          // j adds 0..3 (same 2048-page)
      size_t bh16 = (size_t)((gr0 >> 11) * 16 + h);
      int s0 = gr0 & 2047;
      if (t == 0) {
#pragma unroll
        for (int j = 0; j < 4; ++j)
          qb[(bh16 * SEQ + s0 + j) * HID + dh] = f2bf(v4[j] * QSCALE);
      } else if (t == 1) {
#pragma unroll
        for (int j = 0; j < 4; ++j) {
          size_t hidx = (bh16 * SEQ + s0 + j) * HID + dh;
          kb[hidx] = f2bf(v4[j]);
          present[hidx] = v4[j];
        }
      } else {
        u16x4 pk;
#pragma unroll
        for (int j = 0; j < 4; ++j) pk[j] = f2bf(v4[j]);
        *(u16x4*)&vt[(bh16 * HID + dh) * SEQ + s0] = pk;  // 4 consecutive s, 8B
#pragma unroll
        for (int j = 0; j < 4; ++j)
          present[(size_t)PRESENT_HALF + (bh16 * SEQ + s0 + j) * HID + dh] = v4[j];
      }
    }
}

// ---------- proj GEMM ----------
__global__ void k_gemm_proj(const u16* __restrict__ A, const u16* __restrict__ Bt,
                            const float* __restrict__ bias, float* __restrict__ out) {
  __shared__ __attribute__((aligned(16))) u16 As[3 * 4096];
  __shared__ __attribute__((aligned(16))) u16 Bs[3 * 4096];
  f32x4 acc[4][4];
#pragma unroll
  for (int m = 0; m < 4; ++m)
#pragma unroll
    for (int n = 0; n < 4; ++n) acc[m][n] = {0.f, 0.f, 0.f, 0.f};
  int bx = blockIdx.x, by = blockIdx.y;
  xcd_swz(8, 32, bx, by);
  int brow = by * 128, bcol = bx * 128;
  gemm_core(A, Bt, EMB, brow, bcol, As, Bs, acc);
  int tid = threadIdx.x, lane = tid & 63, wid = tid >> 6;
  int wr = (wid >> 1) * 64, wc = (wid & 1) * 64;
  int r = lane & 15, rj = (lane >> 4) * 4;
#pragma unroll
  for (int m = 0; m < 4; ++m)
#pragma unroll
    for (int n = 0; n < 4; ++n) {
      int gc = bcol + wc + n * 16 + r;
      float bv = bias[gc];
#pragma unroll
      for (int j = 0; j < 4; ++j) {
        int gr = brow + wr + m * 16 + rj + j;
        out[(size_t)gr * EMB + gc] = acc[m][n][j] + bv;
      }
    }
}

// ---------- causal flash attention: one 64-row q-tile per block (round-13
// verified).  Grid 1024 blocks = 4 resident/CU (LDS 40KB); co-resident
// blocks {c,c+256,c+512,c+768} get t = {31-s, 16+s, 15-s, s} (per-CU
// iteration sum = 62 const) and share bh.
__global__ __launch_bounds__(256, 4) void k_attn(
    const u16* __restrict__ qb, const u16* __restrict__ kb,
    const u16* __restrict__ vt, u16* __restrict__ ao) {
  __shared__ __attribute__((aligned(16))) u16 Ks[2][4096];
  __shared__ __attribute__((aligned(16))) u16 Vs[2][4096];  // V^T tiles [dh][k]
  __shared__ __attribute__((aligned(16))) u16 Ps[4096];     // 4 waves x 2KB
  int tid = threadIdx.x, lane = tid & 63, w = tid >> 6;
  int r = lane & 15, g = lane >> 4, kkb = g * 16;
  int bid = blockIdx.x;
  int chunk = bid >> 8, tsub = (bid >> 5) & 7, bh = bid & 31;
  int t = (chunk == 0) ? (31 - tsub)
        : (chunk == 1) ? (16 + tsub)
        : (chunk == 2) ? (15 - tsub) : tsub;
  int q0 = t * 64;
  int ktmax = t;
  const char* Kbh = (const char*)kb + (size_t)bh * SEQ * 128;      // tile kt at +kt*8192
  const char* Vbh = (const char*)vt + (size_t)bh * HID * SEQ * 2;  // row stride 4096B

  // Q fragments (Q pre-scaled by 1/8*log2e)
  size_t qr = (size_t)bh * SEQ + q0 + w * 16 + r;
  bf16x8 aq0 = *(const bf16x8*)((const char*)qb + qr * 128 + kkb);
  bf16x8 aq1 = *(const bf16x8*)((const char*)qb + qr * 128 + 64 + kkb);

  f32x4 o[4];
  float l[4];
#pragma unroll
  for (int d = 0; d < 4; ++d) o[d] = {0.f, 0.f, 0.f, 0.f};
#pragma unroll
  for (int j = 0; j < 4; ++j) l[j] = 0.f;

  // staging addresses: linear LDS dest, inverse-swizzled global source (rule #21)
  int lin0 = tid * 16, lin1 = lin0 + 4096;
  int ks0 = lin0 ^ (((lin0 >> 7) & 7) << 4);
  int ks1 = lin1 ^ (((lin1 >> 7) & 7) << 4);
  int vr0 = lin0 >> 7, vc0 = (lin0 & 127) ^ ((vr0 & 7) << 4);
  int vr1 = lin1 >> 7, vc1 = (lin1 & 127) ^ ((vr1 & 7) << 4);

#define STAGE(kt, b) do {                                             \
    const char* Kg = Kbh + (size_t)(kt) * 8192;                       \
    gload16(Kg + ks0, (char*)Ks[b] + lin0);                           \
    gload16(Kg + ks1, (char*)Ks[b] + lin1);                           \
    const char* Vg = Vbh + (size_t)(kt) * 128;                        \
    gload16(Vg + (size_t)vr0 * 4096 + vc0, (char*)Vs[b] + lin0);      \
    gload16(Vg + (size_t)vr1 * 4096 + vc1, (char*)Vs[b] + lin1);      \
  } while (0)

  char* Pw = (char*)Ps + w * 2048;
  int swz = (r & 7) << 4;

  STAGE(0, 0);
  for (int kt = 0; kt <= ktmax; ++kt) {
    int cur = kt & 1;
    if (kt < ktmax) {
      STAGE(kt + 1, cur ^ 1);
      asm volatile("s_waitcnt vmcnt(4)" ::: "memory");
    } else {
      asm volatile("s_waitcnt vmcnt(0)" ::: "memory");
    }
    bar();
    const char* Kc = (const char*)Ks[cur];
    const char* Vc = (const char*)Vs[cur];

    // QK^T
    f32x4 s[4];
    __builtin_amdgcn_s_setprio(1);
#pragma unroll
    for (int kc = 0; kc < 4; ++kc) {
      int rowb = (kc * 16 + r) * 128;
      bf16x8 bk0 = *(const bf16x8*)(Kc + ((rowb + kkb) ^ swz));
      bf16x8 bk1 = *(const bf16x8*)(Kc + ((rowb + 64 + kkb) ^ swz));
      f32x4 sv = {0.f, 0.f, 0.f, 0.f};
      sv = mfma16(aq0, bk0, sv);
      sv = mfma16(aq1, bk1, sv);
      s[kc] = sv;
    }
    __builtin_amdgcn_s_setprio(0);
    // causal mask (diagonal tile only)
    if (kt == ktmax) {
      int qg = q0 + w * 16 + g * 4;
#pragma unroll
      for (int kc = 0; kc < 4; ++kc) {
        int kg = kt * 64 + kc * 16 + r;
#pragma unroll
        for (int j = 0; j < 4; ++j)
          if (kg > qg + j) s[kc][j] = -1e30f;
      }
    }
    // fixed-max softmax: P = exp2(s); per-lane partial row sums, no shuffles.
    // P store = truncating ds_write_b16_d16_hi (zero-VALU bf16 convert).
#pragma unroll
    for (int kc = 0; kc < 4; ++kc)
#pragma unroll
      for (int j = 0; j < 4; ++j) {
        int row = g * 4 + j;
        int byt = (row * 128 + kc * 32 + r * 2) ^ ((row & 7) << 4);
        float pv = __builtin_amdgcn_exp2f(s[kc][j]);
        l[j] += pv;
        st_p_hi(Pw + byt, pv);
      }
    asm volatile("" ::: "memory");  // fence: PV reads must not hoist above P stores
    // PV with shared V fragments
    __builtin_amdgcn_s_setprio(1);
#pragma unroll
    for (int kk2 = 0; kk2 < 2; ++kk2) {
      int pbyt = (r * 128 + kk2 * 64 + kkb) ^ swz;
      bf16x8 ap = *(const bf16x8*)(Pw + pbyt);
#pragma unroll
      for (int d = 0; d < 4; ++d) {
        int vrow = (d * 16 + r) * 128;
        bf16x8 bv = *(const bf16x8*)(Vc + ((vrow + kk2 * 64 + kkb) ^ swz));
        o[d] = mfma16(ap, bv, o[d]);
      }
    }
    __builtin_amdgcn_s_setprio(0);
    // drain DS returns (incl. untracked asm writes) before next DMA overwrite
    asm volatile("s_waitcnt lgkmcnt(0)" ::: "memory");
    bar();
  }
#undef STAGE

  int b = bh >> 4, h = bh & 15;
#pragma unroll
  for (int j = 0; j < 4; ++j) {
    float sr = l[j];
    sr += __shfl_xor(sr, 1);
    sr += __shfl_xor(sr, 2);
    sr += __shfl_xor(sr, 4);
    sr += __shfl_xor(sr, 8);
    float inv = 1.f / sr;
    size_t row = (size_t)b * SEQ + q0 + w * 16 + g * 4 + j;
#pragma unroll
    for (int d = 0; d < 4; ++d)
      ao[row * EMB + h * 64 + d * 16 + r] = f2bf(o[d][j] * inv);
  }
}

// ---------- launch ----------
extern "C" void kernel_launch(void* const* d_in, const int* in_sizes, int n_in,
                              void* d_out, int out_size, void* d_ws, size_t ws_size,
                              hipStream_t stream) {
  const float* x = (const float*)d_in[0];
  const float* W_attn = (const float*)d_in[1];
  const float* b_attn = (const float*)d_in[2];
  const float* W_proj = (const float*)d_in[3];
  const float* b_proj = (const float*)d_in[4];
  float* out = (float*)d_out;
  char* ws = (char*)d_ws;
  u16* xb  = (u16*)(ws + 0);          //  8 MB  x bf16 [4096][1024]
  u16* wat = (u16*)(ws + 8388608);    //  6 MB  W_attn^T bf16 [3072][1024]
  u16* wpt = (u16*)(ws + 14680064);   //  2 MB  W_proj^T bf16 [1024][1024]
  u16* qb  = (u16*)(ws + 16777216);   //  8 MB  q bf16 [B,H,S,64] (pre-scaled)
  u16* kb  = (u16*)(ws + 25165824);   //  8 MB  k bf16 [B,H,S,64]
  u16* vtb = (u16*)(ws + 33554432);   //  8 MB  v^T bf16 [B,H,64,S]
  u16* ao  = (u16*)(ws + 41943040);   //  8 MB  attn out bf16 [4096][1024]
  float* present = out + PRESENT_HALF;

  k_prep<<<dim3(6144), 256, 0, stream>>>(x, xb, W_attn, wat, W_proj, wpt);
  k_gemm_qkv<<<dim3(24, 32), 256, 0, stream>>>(xb, wat, b_attn, qb, kb, vtb, present);
  k_attn<<<dim3(1024), 256, 0, stream>>>(qb, kb, vtb, ao);
  k_gemm_proj<<<dim3(8, 32), 256, 0, stream>>>(ao, wpt, b_proj, out);
}

// Round 16
// 107.042 us; speedup vs baseline: 1.1100x; 1.0213x over previous
//
#include <hip/hip_runtime.h>

typedef unsigned short u16;
typedef __attribute__((ext_vector_type(8))) __bf16 bf16x8;
typedef __attribute__((ext_vector_type(8))) u16 u16x8;
typedef __attribute__((ext_vector_type(4))) u16 u16x4;
typedef __attribute__((ext_vector_type(2))) unsigned int u32x2;
typedef __attribute__((ext_vector_type(4))) float f32x4;

#define DEV __device__ __forceinline__

// ---------- helpers ----------
DEV u16 f2bf(float f) {  // RTNE fp32 -> bf16
  union { float f; unsigned u; } x; x.f = f;
  unsigned u = x.u;
  u += 0x7fffu + ((u >> 16) & 1u);
  return (u16)(u >> 16);
}

DEV void gload16(const void* g, void* l) {  // async global->LDS, 16B/lane
  __builtin_amdgcn_global_load_lds(
      (const __attribute__((address_space(1))) void*)g,
      (__attribute__((address_space(3))) void*)l, 16, 0, 0);
}

DEV f32x4 mfma16(bf16x8 a, bf16x8 b, f32x4 c) {
  return __builtin_amdgcn_mfma_f32_16x16x32_bf16(a, b, c, 0, 0, 0);
}

DEV void bar() {
  asm volatile("" ::: "memory");
  __builtin_amdgcn_s_barrier();
  asm volatile("" ::: "memory");
}

// pack 4 f32 -> 4 bf16 (v_cvt_pk_bf16_f32) and store as one ds_write_b64
DEV void st_p4(void* lptr, float p0, float p1, float p2, float p3) {
  unsigned a3 = (unsigned)(size_t)(__attribute__((address_space(3))) void*)lptr;
  unsigned lo, hi;
  asm("v_cvt_pk_bf16_f32 %0, %1, %2" : "=v"(lo) : "v"(p0), "v"(p1));
  asm("v_cvt_pk_bf16_f32 %0, %1, %2" : "=v"(hi) : "v"(p2), "v"(p3));
  u32x2 d; d[0] = lo; d[1] = hi;
  asm volatile("ds_write_b64 %0, %1" :: "v"(a3), "v"(d));
}

// ---------- sizes ----------
#define SEQ   2048
#define EMB   1024
#define MROWS 4096            // B*S
#define NQKV  3072
#define HID   64              // head dim
#define PRESENT_HALF 4194304  // B*H*S*Dh elements
// fold 1/sqrt(64) * log2(e) into Q so softmax uses exp2 directly
#define QSCALE 0.1803368801f

// ---------- merged prep: x convert + both weight transposes, one launch ----
DEV void transpose_tile(const float* __restrict__ src, u16* __restrict__ dst,
                        int K, int N, int bx, int by, u16 (*t)[33]) {
  int n0 = bx * 32, k0 = by * 32;
  for (int i = threadIdx.x; i < 1024; i += 256) {
    int r = i >> 5, c = i & 31;
    t[r][c] = f2bf(src[(size_t)(k0 + r) * N + (n0 + c)]);
  }
  __syncthreads();
  for (int i = threadIdx.x; i < 1024; i += 256) {
    int r = i >> 5, c = i & 31;
    dst[(size_t)(n0 + r) * K + (k0 + c)] = t[c][r];
  }
}

__global__ void k_prep(const float* __restrict__ x, u16* __restrict__ xb,
                       const float* __restrict__ W_attn, u16* __restrict__ wat,
                       const float* __restrict__ W_proj, u16* __restrict__ wpt) {
  __shared__ __attribute__((aligned(16))) u16 t[32][33];
  int bid = blockIdx.x;
  if (bid < 2048) {
    int i = bid * 256 + threadIdx.x;  // < 524288
    const float4* s = (const float4*)x + (size_t)i * 2;
    float4 a = s[0], b = s[1];
    u16x8 r;
    r[0] = f2bf(a.x); r[1] = f2bf(a.y); r[2] = f2bf(a.z); r[3] = f2bf(a.w);
    r[4] = f2bf(b.x); r[5] = f2bf(b.y); r[6] = f2bf(b.z); r[7] = f2bf(b.w);
    *((u16x8*)xb + i) = r;
  } else if (bid < 5120) {
    int b = bid - 2048;  // 96 x 32 tiles
    transpose_tile(W_attn, wat, EMB, NQKV, b % 96, b / 96, t);
  } else {
    int b = bid - 5120;  // 32 x 32 tiles
    transpose_tile(W_proj, wpt, EMB, EMB, b % 32, b / 32, t);
  }
}

// ---------- shared GEMM core: C[128,128] tile, 3-buffer 1-ahead pipeline,
// SINGLE barrier per K-step (verified round 13). ----------
DEV void gemm_core(const u16* __restrict__ A, const u16* __restrict__ Bt, int K,
                   int brow, int bcol, u16* As, u16* Bs, f32x4 acc[4][4]) {
  int tid = threadIdx.x, lane = tid & 63, wid = tid >> 6;
  int wr = (wid >> 1) * 64, wc = (wid & 1) * 64;
  int r = lane & 15, kkb = (lane >> 4) * 16;
  const char* Ab = (const char*)(A + (size_t)(brow + (tid >> 2)) * K) + (tid & 3) * 16;
  const char* Bb = (const char*)(Bt + (size_t)(bcol + (tid >> 2)) * K) + (tid & 3) * 16;
  char* Ad = (char*)As + tid * 16;
  char* Bd = (char*)Bs + tid * 16;
  const size_t rowskip = (size_t)64 * K * 2;
#define GSTAGE(k0v, b) do { size_t kb2 = (size_t)(k0v) * 2;            \
    gload16(Ab + kb2, Ad + (b) * 8192);                                \
    gload16(Ab + kb2 + rowskip, Ad + (b) * 8192 + 4096);               \
    gload16(Bb + kb2, Bd + (b) * 8192);                                \
    gload16(Bb + kb2 + rowskip, Bd + (b) * 8192 + 4096); } while (0)
  GSTAGE(0, 0);
  int nk = K >> 5;  // >= 3
  for (int i = 0; i < nk; ++i) {
    int cur = i % 3;
    if (i < nk - 1) {
      GSTAGE((i + 1) << 5, (i + 1) % 3);
      asm volatile("s_waitcnt vmcnt(4)" ::: "memory");  // tile i landed
    } else {
      asm volatile("s_waitcnt vmcnt(0)" ::: "memory");
    }
    bar();
    const char* Ac = (const char*)As + cur * 8192;
    const char* Bc = (const char*)Bs + cur * 8192;
    bf16x8 af[4], bfr[4];
#pragma unroll
    for (int m = 0; m < 4; ++m)
      af[m] = *(const bf16x8*)(Ac + (wr + m * 16 + r) * 64 + kkb);
#pragma unroll
    for (int n = 0; n < 4; ++n)
      bfr[n] = *(const bf16x8*)(Bc + (wc + n * 16 + r) * 64 + kkb);
#pragma unroll
    for (int m = 0; m < 4; ++m)
#pragma unroll
      for (int n = 0; n < 4; ++n)
        acc[m][n] = mfma16(af[m], bfr[n], acc[m][n]);
    // no tail barrier: NB=3 with 1-ahead prefetch makes the WAR window empty
  }
#undef GSTAGE
}

// XCD-aware bijective block swizzle (grid size divisible by 8)
DEV void xcd_swz(int nbx, int nby, int& bx, int& by) {
  int nwg = nbx * nby;
  int bid = by * nbx + bx;
  int cpx = nwg >> 3;
  int s = (bid & 7) * cpx + (bid >> 3);
  bx = s % nbx;
  by = s / nbx;
}

// ---------- QKV GEMM + scatter epilogue (V written pre-transposed) ----------
__global__ void k_gemm_qkv(const u16* __restrict__ A, const u16* __restrict__ Bt,
                           const float* __restrict__ bias, u16* __restrict__ qb,
                           u16* __restrict__ kb, u16* __restrict__ vt,
                           float* __restrict__ present) {
  __shared__ __attribute__((aligned(16))) u16 As[3 * 4096];
  __shared__ __attribute__((aligned(16))) u16 Bs[3 * 4096];
  f32x4 acc[4][4];
#pragma unroll
  for (int m = 0; m < 4; ++m)
#pragma unroll
    for (int n = 0; n < 4; ++n) acc[m][n] = {0.f, 0.f, 0.f, 0.f};
  int bx = blockIdx.x, by = blockIdx.y;
  xcd_swz(24, 32, bx, by);
  int brow = by * 128, bcol = bx * 128;
  gemm_core(A, Bt, EMB, brow, bcol, As, Bs, acc);
  int tid = threadIdx.x, lane = tid & 63, wid = tid >> 6;
  int wr = (wid >> 1) * 64, wc = (wid & 1) * 64;
  int r = lane & 15, rj = (lane >> 4) * 4;
#pragma unroll
  for (int m = 0; m < 4; ++m)
#pragma unroll
    for (int n = 0; n < 4; ++n) {
      int gc = bcol + wc + n * 16 + r;
      int t = gc >> 10, e = gc & 1023, h = e >> 6, dh = e & 63;
      float bv = bias[gc];
      float v4[4];
#pragma unroll
      for (int j = 0; j < 4; ++j) v4[j] = acc[m][n][j] + bv;
      int gr0 = brow + wr + m * 16 + rj;          // j adds 0..3 (same 2048-page)
      size_t bh16 = (size_t)((gr0 >> 11) * 16 + h);
      int s0 = gr0 & 2047;
      if (t == 0) {
#pragma unroll
        for (int j = 0; j < 4; ++j)
          qb[(bh16 * SEQ + s0 + j) * HID + dh] = f2bf(v4[j] * QSCALE);
      } else if (t == 1) {
#pragma unroll
        for (int j = 0; j < 4; ++j) {
          size_t hidx = (bh16 * SEQ + s0 + j) * HID + dh;
          kb[hidx] = f2bf(v4[j]);
          present[hidx] = v4[j];
        }
      } else {
        u16x4 pk;
#pragma unroll
        for (int j = 0; j < 4; ++j) pk[j] = f2bf(v4[j]);
        *(u16x4*)&vt[(bh16 * HID + dh) * SEQ + s0] = pk;  // 4 consecutive s, 8B
#pragma unroll
        for (int j = 0; j < 4; ++j)
          present[(size_t)PRESENT_HALF + (bh16 * SEQ + s0 + j) * HID + dh] = v4[j];
      }
    }
}

// ---------- proj GEMM ----------
__global__ void k_gemm_proj(const u16* __restrict__ A, const u16* __restrict__ Bt,
                            const float* __restrict__ bias, float* __restrict__ out) {
  __shared__ __attribute__((aligned(16))) u16 As[3 * 4096];
  __shared__ __attribute__((aligned(16))) u16 Bs[3 * 4096];
  f32x4 acc[4][4];
#pragma unroll
  for (int m = 0; m < 4; ++m)
#pragma unroll
    for (int n = 0; n < 4; ++n) acc[m][n] = {0.f, 0.f, 0.f, 0.f};
  int bx = blockIdx.x, by = blockIdx.y;
  xcd_swz(8, 32, bx, by);
  int brow = by * 128, bcol = bx * 128;
  gemm_core(A, Bt, EMB, brow, bcol, As, Bs, acc);
  int tid = threadIdx.x, lane = tid & 63, wid = tid >> 6;
  int wr = (wid >> 1) * 64, wc = (wid & 1) * 64;
  int r = lane & 15, rj = (lane >> 4) * 4;
#pragma unroll
  for (int m = 0; m < 4; ++m)
#pragma unroll
    for (int n = 0; n < 4; ++n) {
      int gc = bcol + wc + n * 16 + r;
      float bv = bias[gc];
#pragma unroll
      for (int j = 0; j < 4; ++j) {
        int gr = brow + wr + m * 16 + rj + j;
        out[(size_t)gr * EMB + gc] = acc[m][n][j] + bv;
      }
    }
}

// ---------- causal flash attention: one 64-row q-tile per block.
// Grid 1024 blocks = 4 resident/CU (LDS 40KB); co-resident blocks
// {c,c+256,c+512,c+768} get t = {31-s, 16+s, 15-s, s} (per-CU iteration
// sum = 62 const) and share bh.
// Round-16 delta: SWAPPED QK^T operands -> lane (r,g) holds P[q=r][k=kc*16+
// g*4+j] (4 consecutive k) -> P store is 4x ds_write_b64 of cvt_pk pairs
// (was 16 scalar b16 writes); denominator is one per-lane scalar reduced
// once at the end.  P LDS layout and the whole PV side are unchanged.
__global__ __launch_bounds__(256, 4) void k_attn(
    const u16* __restrict__ qb, const u16* __restrict__ kb,
    const u16* __restrict__ vt, u16* __restrict__ ao) {
  __shared__ __attribute__((aligned(16))) u16 Ks[2][4096];
  __shared__ __attribute__((aligned(16))) u16 Vs[2][4096];  // V^T tiles [dh][k]
  __shared__ __attribute__((aligned(16))) u16 Ps[4096];     // 4 waves x 2KB
  int tid = threadIdx.x, lane = tid & 63, w = tid >> 6;
  int r = lane & 15, g = lane >> 4, kkb = g * 16;
  int bid = blockIdx.x;
  int chunk = bid >> 8, tsub = (bid >> 5) & 7, bh = bid & 31;
  int t = (chunk == 0) ? (31 - tsub)
        : (chunk == 1) ? (16 + tsub)
        : (chunk == 2) ? (15 - tsub) : tsub;
  int q0 = t * 64;
  int ktmax = t;
  const char* Kbh = (const char*)kb + (size_t)bh * SEQ * 128;      // tile kt at +kt*8192
  const char* Vbh = (const char*)vt + (size_t)bh * HID * SEQ * 2;  // row stride 4096B

  // Q fragments (Q pre-scaled by 1/8*log2e)
  size_t qr = (size_t)bh * SEQ + q0 + w * 16 + r;
  bf16x8 aq0 = *(const bf16x8*)((const char*)qb + qr * 128 + kkb);
  bf16x8 aq1 = *(const bf16x8*)((const char*)qb + qr * 128 + 64 + kkb);

  f32x4 o[4];
  float lsum = 0.f;   // per-lane partial denominator for q-row r
#pragma unroll
  for (int d = 0; d < 4; ++d) o[d] = {0.f, 0.f, 0.f, 0.f};

  // staging addresses: linear LDS dest, inverse-swizzled global source (rule #21)
  int lin0 = tid * 16, lin1 = lin0 + 4096;
  int ks0 = lin0 ^ (((lin0 >> 7) & 7) << 4);
  int ks1 = lin1 ^ (((lin1 >> 7) & 7) << 4);
  int vr0 = lin0 >> 7, vc0 = (lin0 & 127) ^ ((vr0 & 7) << 4);
  int vr1 = lin1 >> 7, vc1 = (lin1 & 127) ^ ((vr1 & 7) << 4);

#define STAGE(kt, b) do {                                             \
    const char* Kg = Kbh + (size_t)(kt) * 8192;                       \
    gload16(Kg + ks0, (char*)Ks[b] + lin0);                           \
    gload16(Kg + ks1, (char*)Ks[b] + lin1);                           \
    const char* Vg = Vbh + (size_t)(kt) * 128;                        \
    gload16(Vg + (size_t)vr0 * 4096 + vc0, (char*)Vs[b] + lin0);      \
    gload16(Vg + (size_t)vr1 * 4096 + vc1, (char*)Vs[b] + lin1);      \
  } while (0)

  char* Pw = (char*)Ps + w * 2048;
  int swz = (r & 7) << 4;

  STAGE(0, 0);
  for (int kt = 0; kt <= ktmax; ++kt) {
    int cur = kt & 1;
    if (kt < ktmax) {
      STAGE(kt + 1, cur ^ 1);
      asm volatile("s_waitcnt vmcnt(4)" ::: "memory");
    } else {
      asm volatile("s_waitcnt vmcnt(0)" ::: "memory");
    }
    bar();
    const char* Kc = (const char*)Ks[cur];
    const char* Vc = (const char*)Vs[cur];

    // QK^T, swapped operands: s[kc][j] = S[k = kt*64+kc*16+g*4+j][q-row r]
    f32x4 s[4];
    __builtin_amdgcn_s_setprio(1);
#pragma unroll
    for (int kc = 0; kc < 4; ++kc) {
      int rowb = (kc * 16 + r) * 128;
      bf16x8 bk0 = *(const bf16x8*)(Kc + ((rowb + kkb) ^ swz));
      bf16x8 bk1 = *(const bf16x8*)(Kc + ((rowb + 64 + kkb) ^ swz));
      f32x4 sv = {0.f, 0.f, 0.f, 0.f};
      sv = mfma16(bk0, aq0, sv);
      sv = mfma16(bk1, aq1, sv);
      s[kc] = sv;
    }
    __builtin_amdgcn_s_setprio(0);
    // causal mask (diagonal tile only): mask where k > q
    if (kt == ktmax) {
      int qg = q0 + w * 16 + r;
#pragma unroll
      for (int kc = 0; kc < 4; ++kc) {
        int kg = kt * 64 + kc * 16 + g * 4;
#pragma unroll
        for (int j = 0; j < 4; ++j)
          if (kg + j > qg) s[kc][j] = -1e30f;
      }
    }
    // fixed-max softmax: P = exp2(s); packed b64 P-store (4 bf16 per write)
#pragma unroll
    for (int kc = 0; kc < 4; ++kc) {
      float p0 = __builtin_amdgcn_exp2f(s[kc][0]);
      float p1 = __builtin_amdgcn_exp2f(s[kc][1]);
      float p2 = __builtin_amdgcn_exp2f(s[kc][2]);
      float p3 = __builtin_amdgcn_exp2f(s[kc][3]);
      lsum += (p0 + p1) + (p2 + p3);
      int byt = (r * 128 + kc * 32 + g * 8) ^ swz;
      st_p4(Pw + byt, p0, p1, p2, p3);
    }
    asm volatile("" ::: "memory");  // fence: PV reads must not hoist above P stores
    // PV with shared V fragments (unchanged)
    __builtin_amdgcn_s_setprio(1);
#pragma unroll
    for (int kk2 = 0; kk2 < 2; ++kk2) {
      int pbyt = (r * 128 + kk2 * 64 + kkb) ^ swz;
      bf16x8 ap = *(const bf16x8*)(Pw + pbyt);
#pragma unroll
      for (int d = 0; d < 4; ++d) {
        int vrow = (d * 16 + r) * 128;
        bf16x8 bv = *(const bf16x8*)(Vc + ((vrow + kk2 * 64 + kkb) ^ swz));
        o[d] = mfma16(ap, bv, o[d]);
      }
    }
    __builtin_amdgcn_s_setprio(0);
    // drain DS returns (incl. untracked asm writes) before next DMA overwrite
    asm volatile("s_waitcnt lgkmcnt(0)" ::: "memory");
    bar();
  }
#undef STAGE

  int b = bh >> 4, h = bh & 15;
  // reduce row-r partials over the 4 g-lanes (lanes r, r+16, r+32, r+48)
  float sr = lsum;
  sr += __shfl_xor(sr, 16);
  sr += __shfl_xor(sr, 32);
#pragma unroll
  for (int j = 0; j < 4; ++j) {
    float inv = 1.f / __shfl(sr, g * 4 + j);  // lane g*4+j holds row g*4+j total
    size_t row = (size_t)b * SEQ + q0 + w * 16 + g * 4 + j;
#pragma unroll
    for (int d = 0; d < 4; ++d)
      ao[row * EMB + h * 64 + d * 16 + r] = f2bf(o[d][j] * inv);
  }
}

// ---------- launch ----------
extern "C" void kernel_launch(void* const* d_in, const int* in_sizes, int n_in,
                              void* d_out, int out_size, void* d_ws, size_t ws_size,
                              hipStream_t stream) {
  const float* x = (const float*)d_in[0];
  const float* W_attn = (const float*)d_in[1];
  const float* b_attn = (const float*)d_in[2];
  const float* W_proj = (const float*)d_in[3];
  const float* b_proj = (const float*)d_in[4];
  float* out = (float*)d_out;
  char* ws = (char*)d_ws;
  u16* xb  = (u16*)(ws + 0);          //  8 MB  x bf16 [4096][1024]
  u16* wat = (u16*)(ws + 8388608);    //  6 MB  W_attn^T bf16 [3072][1024]
  u16* wpt = (u16*)(ws + 14680064);   //  2 MB  W_proj^T bf16 [1024][1024]
  u16* qb  = (u16*)(ws + 16777216);   //  8 MB  q bf16 [B,H,S,64] (pre-scaled)
  u16* kb  = (u16*)(ws + 25165824);   //  8 MB  k bf16 [B,H,S,64]
  u16* vtb = (u16*)(ws + 33554432);   //  8 MB  v^T bf16 [B,H,64,S]
  u16* ao  = (u16*)(ws + 41943040);   //  8 MB  attn out bf16 [4096][1024]
  float* present = out + PRESENT_HALF;

  k_prep<<<dim3(6144), 256, 0, stream>>>(x, xb, W_attn, wat, W_proj, wpt);
  k_gemm_qkv<<<dim3(24, 32), 256, 0, stream>>>(xb, wat, b_attn, qb, kb, vtb, present);
  k_attn<<<dim3(1024), 256, 0, stream>>>(qb, kb, vtb, ao);
  k_gemm_proj<<<dim3(8, 32), 256, 0, stream>>>(ao, wpt, b_proj, out);
}

// Round 17
// 106.332 us; speedup vs baseline: 1.1174x; 1.0067x over previous
//
#include <hip/hip_runtime.h>

typedef unsigned short u16;
typedef __attribute__((ext_vector_type(8))) __bf16 bf16x8;
typedef __attribute__((ext_vector_type(8))) u16 u16x8;
typedef __attribute__((ext_vector_type(4))) u16 u16x4;
typedef __attribute__((ext_vector_type(2))) unsigned int u32x2;
typedef __attribute__((ext_vector_type(4))) float f32x4;

#define DEV __device__ __forceinline__

// ---------- helpers ----------
DEV u16 f2bf(float f) {  // RTNE fp32 -> bf16
  union { float f; unsigned u; } x; x.f = f;
  unsigned u = x.u;
  u += 0x7fffu + ((u >> 16) & 1u);
  return (u16)(u >> 16);
}

DEV void gload16(const void* g, void* l) {  // async global->LDS, 16B/lane
  __builtin_amdgcn_global_load_lds(
      (const __attribute__((address_space(1))) void*)g,
      (__attribute__((address_space(3))) void*)l, 16, 0, 0);
}

DEV f32x4 mfma16(bf16x8 a, bf16x8 b, f32x4 c) {
  return __builtin_amdgcn_mfma_f32_16x16x32_bf16(a, b, c, 0, 0, 0);
}

DEV void bar() {
  asm volatile("" ::: "memory");
  __builtin_amdgcn_s_barrier();
  asm volatile("" ::: "memory");
}

// pack 4 f32 -> 4 bf16 (v_cvt_pk_bf16_f32) and store as one ds_write_b64
DEV void st_p4(void* lptr, float p0, float p1, float p2, float p3) {
  unsigned a3 = (unsigned)(size_t)(__attribute__((address_space(3))) void*)lptr;
  unsigned lo, hi;
  asm("v_cvt_pk_bf16_f32 %0, %1, %2" : "=v"(lo) : "v"(p0), "v"(p1));
  asm("v_cvt_pk_bf16_f32 %0, %1, %2" : "=v"(hi) : "v"(p2), "v"(p3));
  u32x2 d; d[0] = lo; d[1] = hi;
  asm volatile("ds_write_b64 %0, %1" :: "v"(a3), "v"(d));
}

// ---------- sizes ----------
#define SEQ   2048
#define EMB   1024
#define MROWS 4096            // B*S
#define NQKV  3072
#define HID   64              // head dim
#define PRESENT_HALF 4194304  // B*H*S*Dh elements
// fold 1/sqrt(64) * log2(e) into Q so softmax uses exp2 directly
#define QSCALE 0.1803368801f

// ---------- merged prep: x convert + both weight transposes, one launch ----
DEV void transpose_tile(const float* __restrict__ src, u16* __restrict__ dst,
                        int K, int N, int bx, int by, u16 (*t)[33]) {
  int n0 = bx * 32, k0 = by * 32;
  for (int i = threadIdx.x; i < 1024; i += 256) {
    int r = i >> 5, c = i & 31;
    t[r][c] = f2bf(src[(size_t)(k0 + r) * N + (n0 + c)]);
  }
  __syncthreads();
  for (int i = threadIdx.x; i < 1024; i += 256) {
    int r = i >> 5, c = i & 31;
    dst[(size_t)(n0 + r) * K + (k0 + c)] = t[c][r];
  }
}

__global__ void k_prep(const float* __restrict__ x, u16* __restrict__ xb,
                       const float* __restrict__ W_attn, u16* __restrict__ wat,
                       const float* __restrict__ W_proj, u16* __restrict__ wpt) {
  __shared__ __attribute__((aligned(16))) u16 t[32][33];
  int bid = blockIdx.x;
  if (bid < 2048) {
    int i = bid * 256 + threadIdx.x;  // < 524288
    const float4* s = (const float4*)x + (size_t)i * 2;
    float4 a = s[0], b = s[1];
    u16x8 r;
    r[0] = f2bf(a.x); r[1] = f2bf(a.y); r[2] = f2bf(a.z); r[3] = f2bf(a.w);
    r[4] = f2bf(b.x); r[5] = f2bf(b.y); r[6] = f2bf(b.z); r[7] = f2bf(b.w);
    *((u16x8*)xb + i) = r;
  } else if (bid < 5120) {
    int b = bid - 2048;  // 96 x 32 tiles
    transpose_tile(W_attn, wat, EMB, NQKV, b % 96, b / 96, t);
  } else {
    int b = bid - 5120;  // 32 x 32 tiles
    transpose_tile(W_proj, wpt, EMB, EMB, b % 32, b / 32, t);
  }
}

// ---------- shared GEMM core: C[128,128] tile, 3-buffer 1-ahead pipeline,
// SINGLE barrier per K-step (round 13).  Round-17 delta: chunk-XOR swizzle
// on the fragment layout — LDS (row, chunk c) holds global k-chunk
// c ^ ((row>>1)&3); staged via pre-swizzled global source (rule #21: linear
// LDS dest), read via lane-constant XOR srd = ((r>>1)&3)<<4.  Spreads each
// g-group's 16 lanes across all (parity, chunk) 4-bank groups ->
// minimum-aliasing ds_read_b128 (was ~8-way). ----------
DEV void gemm_core(const u16* __restrict__ A, const u16* __restrict__ Bt, int K,
                   int brow, int bcol, u16* As, u16* Bs, f32x4 acc[4][4]) {
  int tid = threadIdx.x, lane = tid & 63, wid = tid >> 6;
  int wr = (wid >> 1) * 64, wc = (wid & 1) * 64;
  int r = lane & 15, kkb = (lane >> 4) * 16;
  int srd = ((r >> 1) & 3) << 4;                  // read-side chunk swizzle
  int ch = ((tid & 3) ^ ((tid >> 3) & 3)) * 16;   // staged-source chunk swizzle
  const char* Ab = (const char*)(A + (size_t)(brow + (tid >> 2)) * K) + ch;
  const char* Bb = (const char*)(Bt + (size_t)(bcol + (tid >> 2)) * K) + ch;
  char* Ad = (char*)As + tid * 16;
  char* Bd = (char*)Bs + tid * 16;
  const size_t rowskip = (size_t)64 * K * 2;
#define GSTAGE(k0v, b) do { size_t kb2 = (size_t)(k0v) * 2;            \
    gload16(Ab + kb2, Ad + (b) * 8192);                                \
    gload16(Ab + kb2 + rowskip, Ad + (b) * 8192 + 4096);               \
    gload16(Bb + kb2, Bd + (b) * 8192);                                \
    gload16(Bb + kb2 + rowskip, Bd + (b) * 8192 + 4096); } while (0)
  GSTAGE(0, 0);
  int nk = K >> 5;  // >= 3
  for (int i = 0; i < nk; ++i) {
    int cur = i % 3;
    if (i < nk - 1) {
      GSTAGE((i + 1) << 5, (i + 1) % 3);
      asm volatile("s_waitcnt vmcnt(4)" ::: "memory");  // tile i landed
    } else {
      asm volatile("s_waitcnt vmcnt(0)" ::: "memory");
    }
    bar();
    const char* Ac = (const char*)As + cur * 8192;
    const char* Bc = (const char*)Bs + cur * 8192;
    bf16x8 af[4], bfr[4];
#pragma unroll
    for (int m = 0; m < 4; ++m)
      af[m] = *(const bf16x8*)(Ac + (wr + m * 16 + r) * 64 + (kkb ^ srd));
#pragma unroll
    for (int n = 0; n < 4; ++n)
      bfr[n] = *(const bf16x8*)(Bc + (wc + n * 16 + r) * 64 + (kkb ^ srd));
#pragma unroll
    for (int m = 0; m < 4; ++m)
#pragma unroll
      for (int n = 0; n < 4; ++n)
        acc[m][n] = mfma16(af[m], bfr[n], acc[m][n]);
    // no tail barrier: NB=3 with 1-ahead prefetch makes the WAR window empty
  }
#undef GSTAGE
}

// XCD-aware bijective block swizzle (grid size divisible by 8)
DEV void xcd_swz(int nbx, int nby, int& bx, int& by) {
  int nwg = nbx * nby;
  int bid = by * nbx + bx;
  int cpx = nwg >> 3;
  int s = (bid & 7) * cpx + (bid >> 3);
  bx = s % nbx;
  by = s / nbx;
}

// ---------- QKV GEMM + scatter epilogue (V written pre-transposed) ----------
__global__ void k_gemm_qkv(const u16* __restrict__ A, const u16* __restrict__ Bt,
                           const float* __restrict__ bias, u16* __restrict__ qb,
                           u16* __restrict__ kb, u16* __restrict__ vt,
                           float* __restrict__ present) {
  __shared__ __attribute__((aligned(16))) u16 As[3 * 4096];
  __shared__ __attribute__((aligned(16))) u16 Bs[3 * 4096];
  f32x4 acc[4][4];
#pragma unroll
  for (int m = 0; m < 4; ++m)
#pragma unroll
    for (int n = 0; n < 4; ++n) acc[m][n] = {0.f, 0.f, 0.f, 0.f};
  int bx = blockIdx.x, by = blockIdx.y;
  xcd_swz(24, 32, bx, by);
  int brow = by * 128, bcol = bx * 128;
  gemm_core(A, Bt, EMB, brow, bcol, As, Bs, acc);
  int tid = threadIdx.x, lane = tid & 63, wid = tid >> 6;
  int wr = (wid >> 1) * 64, wc = (wid & 1) * 64;
  int r = lane & 15, rj = (lane >> 4) * 4;
#pragma unroll
  for (int m = 0; m < 4; ++m)
#pragma unroll
    for (int n = 0; n < 4; ++n) {
      int gc = bcol + wc + n * 16 + r;
      int t = gc >> 10, e = gc & 1023, h = e >> 6, dh = e & 63;
      float bv = bias[gc];
      float v4[4];
#pragma unroll
      for (int j = 0; j < 4; ++j) v4[j] = acc[m][n][j] + bv;
      int gr0 = brow + wr + m * 16 + rj;          // j adds 0..3 (same 2048-page)
      size_t bh16 = (size_t)((gr0 >> 11) * 16 + h);
      int s0 = gr0 & 2047;
      if (t == 0) {
#pragma unroll
        for (int j = 0; j < 4; ++j)
          qb[(bh16 * SEQ + s0 + j) * HID + dh] = f2bf(v4[j] * QSCALE);
      } else if (t == 1) {
#pragma unroll
        for (int j = 0; j < 4; ++j) {
          size_t hidx = (bh16 * SEQ + s0 + j) * HID + dh;
          kb[hidx] = f2bf(v4[j]);
          present[hidx] = v4[j];
        }
      } else {
        u16x4 pk;
#pragma unroll
        for (int j = 0; j < 4; ++j) pk[j] = f2bf(v4[j]);
        *(u16x4*)&vt[(bh16 * HID + dh) * SEQ + s0] = pk;  // 4 consecutive s, 8B
#pragma unroll
        for (int j = 0; j < 4; ++j)
          present[(size_t)PRESENT_HALF + (bh16 * SEQ + s0 + j) * HID + dh] = v4[j];
      }
    }
}

// ---------- proj GEMM ----------
__global__ void k_gemm_proj(const u16* __restrict__ A, const u16* __restrict__ Bt,
                            const float* __restrict__ bias, float* __restrict__ out) {
  __shared__ __attribute__((aligned(16))) u16 As[3 * 4096];
  __shared__ __attribute__((aligned(16))) u16 Bs[3 * 4096];
  f32x4 acc[4][4];
#pragma unroll
  for (int m = 0; m < 4; ++m)
#pragma unroll
    for (int n = 0; n < 4; ++n) acc[m][n] = {0.f, 0.f, 0.f, 0.f};
  int bx = blockIdx.x, by = blockIdx.y;
  xcd_swz(8, 32, bx, by);
  int brow = by * 128, bcol = bx * 128;
  gemm_core(A, Bt, EMB, brow, bcol, As, Bs, acc);
  int tid = threadIdx.x, lane = tid & 63, wid = tid >> 6;
  int wr = (wid >> 1) * 64, wc = (wid & 1) * 64;
  int r = lane & 15, rj = (lane >> 4) * 4;
#pragma unroll
  for (int m = 0; m < 4; ++m)
#pragma unroll
    for (int n = 0; n < 4; ++n) {
      int gc = bcol + wc + n * 16 + r;
      float bv = bias[gc];
#pragma unroll
      for (int j = 0; j < 4; ++j) {
        int gr = brow + wr + m * 16 + rj + j;
        out[(size_t)gr * EMB + gc] = acc[m][n][j] + bv;
      }
    }
}

// ---------- causal flash attention: one 64-row q-tile per block.
// Grid 1024 blocks = 4 resident/CU (LDS 40KB); co-resident blocks
// {c,c+256,c+512,c+768} get t = {31-s, 16+s, 15-s, s} (per-CU iteration
// sum = 62 const) and share bh.  Swapped-QK^T P is lane-local (round 16).
__global__ __launch_bounds__(256, 4) void k_attn(
    const u16* __restrict__ qb, const u16* __restrict__ kb,
    const u16* __restrict__ vt, u16* __restrict__ ao) {
  __shared__ __attribute__((aligned(16))) u16 Ks[2][4096];
  __shared__ __attribute__((aligned(16))) u16 Vs[2][4096];  // V^T tiles [dh][k]
  __shared__ __attribute__((aligned(16))) u16 Ps[4096];     // 4 waves x 2KB
  int tid = threadIdx.x, lane = tid & 63, w = tid >> 6;
  int r = lane & 15, g = lane >> 4, kkb = g * 16;
  int bid = blockIdx.x;
  int chunk = bid >> 8, tsub = (bid >> 5) & 7, bh = bid & 31;
  int t = (chunk == 0) ? (31 - tsub)
        : (chunk == 1) ? (16 + tsub)
        : (chunk == 2) ? (15 - tsub) : tsub;
  int q0 = t * 64;
  int ktmax = t;
  const char* Kbh = (const char*)kb + (size_t)bh * SEQ * 128;      // tile kt at +kt*8192
  const char* Vbh = (const char*)vt + (size_t)bh * HID * SEQ * 2;  // row stride 4096B

  // Q fragments (Q pre-scaled by 1/8*log2e)
  size_t qr = (size_t)bh * SEQ + q0 + w * 16 + r;
  bf16x8 aq0 = *(const bf16x8*)((const char*)qb + qr * 128 + kkb);
  bf16x8 aq1 = *(const bf16x8*)((const char*)qb + qr * 128 + 64 + kkb);

  f32x4 o[4];
  float lsum = 0.f;   // per-lane partial denominator for q-row r
#pragma unroll
  for (int d = 0; d < 4; ++d) o[d] = {0.f, 0.f, 0.f, 0.f};

  // staging addresses: linear LDS dest, inverse-swizzled global source (rule #21)
  int lin0 = tid * 16, lin1 = lin0 + 4096;
  int ks0 = lin0 ^ (((lin0 >> 7) & 7) << 4);
  int ks1 = lin1 ^ (((lin1 >> 7) & 7) << 4);
  int vr0 = lin0 >> 7, vc0 = (lin0 & 127) ^ ((vr0 & 7) << 4);
  int vr1 = lin1 >> 7, vc1 = (lin1 & 127) ^ ((vr1 & 7) << 4);

#define STAGE(kt, b) do {                                             \
    const char* Kg = Kbh + (size_t)(kt) * 8192;                       \
    gload16(Kg + ks0, (char*)Ks[b] + lin0);                           \
    gload16(Kg + ks1, (char*)Ks[b] + lin1);                           \
    const char* Vg = Vbh + (size_t)(kt) * 128;                        \
    gload16(Vg + (size_t)vr0 * 4096 + vc0, (char*)Vs[b] + lin0);      \
    gload16(Vg + (size_t)vr1 * 4096 + vc1, (char*)Vs[b] + lin1);      \
  } while (0)

  char* Pw = (char*)Ps + w * 2048;
  int swz = (r & 7) << 4;

  STAGE(0, 0);
  for (int kt = 0; kt <= ktmax; ++kt) {
    int cur = kt & 1;
    if (kt < ktmax) {
      STAGE(kt + 1, cur ^ 1);
      asm volatile("s_waitcnt vmcnt(4)" ::: "memory");
    } else {
      asm volatile("s_waitcnt vmcnt(0)" ::: "memory");
    }
    bar();
    const char* Kc = (const char*)Ks[cur];
    const char* Vc = (const char*)Vs[cur];

    // QK^T, swapped operands: s[kc][j] = S[k = kt*64+kc*16+g*4+j][q-row r]
    f32x4 s[4];
    __builtin_amdgcn_s_setprio(1);
#pragma unroll
    for (int kc = 0; kc < 4; ++kc) {
      int rowb = (kc * 16 + r) * 128;
      bf16x8 bk0 = *(const bf16x8*)(Kc + ((rowb + kkb) ^ swz));
      bf16x8 bk1 = *(const bf16x8*)(Kc + ((rowb + 64 + kkb) ^ swz));
      f32x4 sv = {0.f, 0.f, 0.f, 0.f};
      sv = mfma16(bk0, aq0, sv);
      sv = mfma16(bk1, aq1, sv);
      s[kc] = sv;
    }
    __builtin_amdgcn_s_setprio(0);
    // causal mask (diagonal tile only): mask where k > q
    if (kt == ktmax) {
      int qg = q0 + w * 16 + r;
#pragma unroll
      for (int kc = 0; kc < 4; ++kc) {
        int kg = kt * 64 + kc * 16 + g * 4;
#pragma unroll
        for (int j = 0; j < 4; ++j)
          if (kg + j > qg) s[kc][j] = -1e30f;
      }
    }
    // fixed-max softmax: P = exp2(s); packed b64 P-store (4 bf16 per write)
#pragma unroll
    for (int kc = 0; kc < 4; ++kc) {
      float p0 = __builtin_amdgcn_exp2f(s[kc][0]);
      float p1 = __builtin_amdgcn_exp2f(s[kc][1]);
      float p2 = __builtin_amdgcn_exp2f(s[kc][2]);
      float p3 = __builtin_amdgcn_exp2f(s[kc][3]);
      lsum += (p0 + p1) + (p2 + p3);
      int byt = (r * 128 + kc * 32 + g * 8) ^ swz;
      st_p4(Pw + byt, p0, p1, p2, p3);
    }
    asm volatile("" ::: "memory");  // fence: PV reads must not hoist above P stores
    // PV with shared V fragments (unchanged)
    __builtin_amdgcn_s_setprio(1);
#pragma unroll
    for (int kk2 = 0; kk2 < 2; ++kk2) {
      int pbyt = (r * 128 + kk2 * 64 + kkb) ^ swz;
      bf16x8 ap = *(const bf16x8*)(Pw + pbyt);
#pragma unroll
      for (int d = 0; d < 4; ++d) {
        int vrow = (d * 16 + r) * 128;
        bf16x8 bv = *(const bf16x8*)(Vc + ((vrow + kk2 * 64 + kkb) ^ swz));
        o[d] = mfma16(ap, bv, o[d]);
      }
    }
    __builtin_amdgcn_s_setprio(0);
    // drain DS returns (incl. untracked asm writes) before next DMA overwrite
    asm volatile("s_waitcnt lgkmcnt(0)" ::: "memory");
    bar();
  }
#undef STAGE

  int b = bh >> 4, h = bh & 15;
  // reduce row-r partials over the 4 g-lanes (lanes r, r+16, r+32, r+48)
  float sr = lsum;
  sr += __shfl_xor(sr, 16);
  sr += __shfl_xor(sr, 32);
#pragma unroll
  for (int j = 0; j < 4; ++j) {
    float inv = 1.f / __shfl(sr, g * 4 + j);  // lane g*4+j holds row g*4+j total
    size_t row = (size_t)b * SEQ + q0 + w * 16 + g * 4 + j;
#pragma unroll
    for (int d = 0; d < 4; ++d)
      ao[row * EMB + h * 64 + d * 16 + r] = f2bf(o[d][j] * inv);
  }
}

// ---------- launch ----------
extern "C" void kernel_launch(void* const* d_in, const int* in_sizes, int n_in,
                              void* d_out, int out_size, void* d_ws, size_t ws_size,
                              hipStream_t stream) {
  const float* x = (const float*)d_in[0];
  const float* W_attn = (const float*)d_in[1];
  const float* b_attn = (const float*)d_in[2];
  const float* W_proj = (const float*)d_in[3];
  const float* b_proj = (const float*)d_in[4];
  float* out = (float*)d_out;
  char* ws = (char*)d_ws;
  u16* xb  = (u16*)(ws + 0);          //  8 MB  x bf16 [4096][1024]
  u16* wat = (u16*)(ws + 8388608);    //  6 MB  W_attn^T bf16 [3072][1024]
  u16* wpt = (u16*)(ws + 14680064);   //  2 MB  W_proj^T bf16 [1024][1024]
  u16* qb  = (u16*)(ws + 16777216);   //  8 MB  q bf16 [B,H,S,64] (pre-scaled)
  u16* kb  = (u16*)(ws + 25165824);   //  8 MB  k bf16 [B,H,S,64]
  u16* vtb = (u16*)(ws + 33554432);   //  8 MB  v^T bf16 [B,H,64,S]
  u16* ao  = (u16*)(ws + 41943040);   //  8 MB  attn out bf16 [4096][1024]
  float* present = out + PRESENT_HALF;

  k_prep<<<dim3(6144), 256, 0, stream>>>(x, xb, W_attn, wat, W_proj, wpt);
  k_gemm_qkv<<<dim3(24, 32), 256, 0, stream>>>(xb, wat, b_attn, qb, kb, vtb, present);
  k_attn<<<dim3(1024), 256, 0, stream>>>(qb, kb, vtb, ao);
  k_gemm_proj<<<dim3(8, 32), 256, 0, stream>>>(ao, wpt, b_proj, out);
}